// Round 7
// baseline (478.310 us; speedup 1.0000x reference)
//
#include <hip/hip_runtime.h>
#include <hip/hip_fp16.h>

#define DIM 64
#define HDIM 32
#define BSH 8                 // log2(nodes per bucket) = 256 nodes/bucket
#define BMASK 255u
#define NBMAX 1024            // max coarse buckets supported
#define BINC 16384            // edges staged per bin block

typedef __attribute__((ext_vector_type(4))) float f32x4;

// ---------------- prep kernels ----------------

__global__ void zero_ints(int* __restrict__ p, int n) {
    int i = blockIdx.x * blockDim.x + threadIdx.x;
    if (i < n) p[i] = 0;
}

// per-block LDS histogram of edges per coarse bucket, flushed with one
// atomicAdd per (block,bucket)
__global__ __launch_bounds__(1024) void bucket_count_kernel(const int* __restrict__ edge, int E,
                                                            int* __restrict__ bcnt, int NB) {
    __shared__ int lcnt[NBMAX];
    for (int i = threadIdx.x; i < NB; i += 1024) lcnt[i] = 0;
    __syncthreads();
    int stride = gridDim.x * 1024;
    for (int i = blockIdx.x * 1024 + threadIdx.x; i < E; i += stride)
        atomicAdd(&lcnt[edge[E + i] >> BSH], 1);
    __syncthreads();
    for (int i = threadIdx.x; i < NB; i += 1024) {
        int v = lcnt[i];
        if (v) atomicAdd(&bcnt[i], v);
    }
}

// single-block exclusive scan over n counts -> offsets[0..n], cursor copy
__global__ __launch_bounds__(1024) void scan_kernel(const int* __restrict__ cnt,
                                                    int* __restrict__ offsets,
                                                    int* __restrict__ cursor,
                                                    int n) {
    __shared__ int lds[1024];
    const int T = 1024, K = 4, CHUNK = T * K;
    int carry = 0;
    for (int base = 0; base < n; base += CHUNK) {
        int v[K];
        int idx0 = base + (int)threadIdx.x * K;
#pragma unroll
        for (int k = 0; k < K; ++k) {
            int i = idx0 + k;
            v[k] = (i < n) ? cnt[i] : 0;
        }
        int tsum = v[0] + v[1] + v[2] + v[3];
        lds[threadIdx.x] = tsum;
        __syncthreads();
        int incl = tsum;
        for (int off = 1; off < T; off <<= 1) {
            int t = (threadIdx.x >= (unsigned)off) ? lds[threadIdx.x - off] : 0;
            __syncthreads();
            incl += t;
            lds[threadIdx.x] = incl;
            __syncthreads();
        }
        int total = lds[T - 1];
        int run = carry + (incl - tsum);
#pragma unroll
        for (int k = 0; k < K; ++k) {
            int i = idx0 + k;
            if (i < n) { offsets[i] = run; cursor[i] = run; }
            run += v[k];
        }
        carry += total;
        __syncthreads();
    }
    if (threadIdx.x == 0) offsets[n] = carry;
}

// LDS-staged scatter: sort a 16K-edge chunk by bucket in LDS, reserve one
// contiguous global range per (block,bucket), copy out per-bucket runs.
// entry = (row << 8) | (col & 255)
__global__ __launch_bounds__(1024) void bin_kernel(const int* __restrict__ edge, int E,
                                                   int* __restrict__ bcur,
                                                   unsigned* __restrict__ bin, int NB) {
    __shared__ unsigned stage[BINC];
    __shared__ int lcnt[NBMAX];
    __shared__ int lsc[NBMAX];
    __shared__ int lcur[NBMAX];
    __shared__ int gb[NBMAX];
    const int tid = (int)threadIdx.x;
    const int beg = (int)blockIdx.x * BINC;
    const int n = min(BINC, E - beg);

    lcnt[tid] = 0;
    __syncthreads();
    // phase 1: count per bucket
    for (int i = tid; i < n; i += 1024)
        atomicAdd(&lcnt[edge[E + beg + i] >> BSH], 1);
    __syncthreads();
    // inclusive scan over 1024 slots
    lsc[tid] = lcnt[tid];
    __syncthreads();
    for (int off = 1; off < 1024; off <<= 1) {
        int t = (tid >= off) ? lsc[tid - off] : 0;
        __syncthreads();
        lsc[tid] += t;
        __syncthreads();
    }
    // reserve global ranges, init local cursors
    {
        int cb = lcnt[tid];
        lcur[tid] = lsc[tid] - cb;            // exclusive base
        if (tid < NB) gb[tid] = cb ? atomicAdd(&bcur[tid], cb) : 0;
    }
    __syncthreads();
    // phase 2: rank into LDS stage (sorted by bucket)
    for (int i = tid; i < n; i += 1024) {
        int r = edge[beg + i];
        int c = edge[E + beg + i];
        int b = c >> BSH;
        int slot = atomicAdd(&lcur[b], 1);
        stage[slot] = ((unsigned)r << BSH) | ((unsigned)c & BMASK);
    }
    __syncthreads();
    // phase 3: per-bucket coalesced-ish copy out
    const int wid = tid >> 6, lane = tid & 63;
    for (int b = wid; b < NB; b += 16) {
        int cb = lcnt[b];
        if (!cb) continue;
        int lb = lsc[b] - cb;
        int g = gb[b];
        for (int l = lane; l < cb; l += 64)
            bin[g + l] = stage[lb + l];
    }
}

// per-bucket counting sort -> CSR + offsets + dinv + rdinv, fused with
// y0 init (y0 = fp16(dinv * emb), split into half-tables A/B)
__global__ __launch_bounds__(256) void csr_kernel(const unsigned* __restrict__ bin,
                                                  const int* __restrict__ boff,
                                                  const float* __restrict__ user,
                                                  const float* __restrict__ item,
                                                  int nU,
                                                  int* __restrict__ offsets,
                                                  float* __restrict__ dinv,
                                                  float* __restrict__ rdinv,
                                                  int* __restrict__ row_sorted,
                                                  __half* __restrict__ y0A,
                                                  __half* __restrict__ y0B,
                                                  int nN) {
    __shared__ int lcnt[256];
    __shared__ int lsc[256];
    __shared__ int lcur[256];
    __shared__ float sdinv[256];
    const int tid = (int)threadIdx.x;
    const int b = (int)blockIdx.x;
    const int beg = boff[b], end = boff[b + 1];
    lcnt[tid] = 0;
    __syncthreads();
    for (int i = beg + tid; i < end; i += 256)
        atomicAdd(&lcnt[bin[i] & BMASK], 1);
    __syncthreads();
    lsc[tid] = lcnt[tid];
    __syncthreads();
    for (int off = 1; off < 256; off <<= 1) {
        int t = (tid >= off) ? lsc[tid - off] : 0;
        __syncthreads();
        lsc[tid] += t;
        __syncthreads();
    }
    int cb = lcnt[tid];
    int lb = lsc[tid] - cb;
    lcur[tid] = lb;
    float dv = cb ? rsqrtf((float)cb) : 0.0f;
    sdinv[tid] = dv;
    int node = (b << BSH) + tid;
    if (node < nN) {
        offsets[node] = beg + lb;
        dinv[node] = dv;
        rdinv[node] = cb ? sqrtf((float)cb) : 0.0f;
        if (node == nN - 1) offsets[nN] = beg + lsc[tid];
    }
    __syncthreads();
    for (int i = beg + tid; i < end; i += 256) {
        unsigned e = bin[i];
        int c = (int)(e & BMASK);
        int p = atomicAdd(&lcur[c], 1);
        row_sorted[beg + p] = (int)(e >> BSH);
    }
    // fused y0 init: 256 nodes x 8 chunks; chunk qc covers dims 8qc..8qc+7
    const int baseNode = b << BSH;
#pragma unroll
    for (int it = 0; it < 8; ++it) {
        int idx = it * 256 + tid;        // chunk within block, 0..2047
        int ln = idx >> 3;               // local node
        int node2 = baseNode + ln;
        if (node2 < nN) {
            int qc = idx & 7;
            const float* src = (node2 < nU) ? user + (size_t)node2 * DIM
                                            : item + (size_t)(node2 - nU) * DIM;
            float4 e0 = ((const float4*)src)[qc * 2];
            float4 e1 = ((const float4*)src)[qc * 2 + 1];
            float dvn = sdinv[ln];
            float4 pack;
            __half2* p = (__half2*)&pack;
            p[0] = __floats2half2_rn(dvn * e0.x, dvn * e0.y);
            p[1] = __floats2half2_rn(dvn * e0.z, dvn * e0.w);
            p[2] = __floats2half2_rn(dvn * e1.x, dvn * e1.y);
            p[3] = __floats2half2_rn(dvn * e1.z, dvn * e1.w);
            float4* dst = (qc < 4)
                ? (float4*)y0A + (size_t)node2 * 4 + qc
                : (float4*)y0B + (size_t)node2 * 4 + (qc - 4);
            *dst = pack;
        }
    }
}

// one pass over HALF the dims: table = [nN][32] fp16 (9.6MB, full 64B lines).
// one wave per node; 16 edge-slots x 4 lanes; lane loads float4 (8 halves);
// 2x unroll = 32 edges in flight. Writes y_out = dinv^2 * sum (nontemporal).
__global__ __launch_bounds__(256) void layer_pass_kernel(const int* __restrict__ offsets,
                                                         const int* __restrict__ row_sorted,
                                                         const float* __restrict__ dinv,
                                                         const __half* __restrict__ y_in,
                                                         __half* __restrict__ y_out,
                                                         int nN) {
    int wave = (int)((blockIdx.x * blockDim.x + threadIdx.x) >> 6);
    int lane = (int)(threadIdx.x & 63);
    if (wave >= nN) return;
    const int beg = offsets[wave];
    const int end = offsets[wave + 1];
    const int g = lane >> 2;   // edge slot 0..15
    const int q = lane & 3;    // 16B chunk of the half-row, 0..3
    const float4* yv = (const float4*)y_in;
    float a0 = 0, a1 = 0, a2 = 0, a3 = 0, a4 = 0, a5 = 0, a6 = 0, a7 = 0;
    const int last = end - 1;
    for (int base = beg; base < end; base += 32) {
        int e0 = base + g;
        int e1 = e0 + 16;
        int i0 = (e0 <= last) ? e0 : last;
        int i1 = (e1 <= last) ? e1 : last;
        float m0 = (e0 <= last) ? 1.0f : 0.0f;
        float m1 = (e1 <= last) ? 1.0f : 0.0f;
        int r0 = __builtin_nontemporal_load(row_sorted + i0);
        int r1 = __builtin_nontemporal_load(row_sorted + i1);
        float4 v0 = yv[(size_t)r0 * 4 + q];
        float4 v1 = yv[(size_t)r1 * 4 + q];
        const __half2* h0 = (const __half2*)&v0;
        const __half2* h1 = (const __half2*)&v1;
        float2 t;
        t = __half22float2(h0[0]); a0 = fmaf(m0, t.x, a0); a1 = fmaf(m0, t.y, a1);
        t = __half22float2(h0[1]); a2 = fmaf(m0, t.x, a2); a3 = fmaf(m0, t.y, a3);
        t = __half22float2(h0[2]); a4 = fmaf(m0, t.x, a4); a5 = fmaf(m0, t.y, a5);
        t = __half22float2(h0[3]); a6 = fmaf(m0, t.x, a6); a7 = fmaf(m0, t.y, a7);
        t = __half22float2(h1[0]); a0 = fmaf(m1, t.x, a0); a1 = fmaf(m1, t.y, a1);
        t = __half22float2(h1[1]); a2 = fmaf(m1, t.x, a2); a3 = fmaf(m1, t.y, a3);
        t = __half22float2(h1[2]); a4 = fmaf(m1, t.x, a4); a5 = fmaf(m1, t.y, a5);
        t = __half22float2(h1[3]); a6 = fmaf(m1, t.x, a6); a7 = fmaf(m1, t.y, a7);
    }
    // reduce across the 16 edge-slots (lane bits 2..5)
#pragma unroll
    for (int ofs = 4; ofs <= 32; ofs <<= 1) {
        a0 += __shfl_xor(a0, ofs);
        a1 += __shfl_xor(a1, ofs);
        a2 += __shfl_xor(a2, ofs);
        a3 += __shfl_xor(a3, ofs);
        a4 += __shfl_xor(a4, ofs);
        a5 += __shfl_xor(a5, ofs);
        a6 += __shfl_xor(a6, ofs);
        a7 += __shfl_xor(a7, ofs);
    }
    if (g == 0) {
        float dc = dinv[wave];
        float s = dc * dc;          // y_out = dinv * (dinv * sum)
        f32x4 pack;
        __half2 ph[4];
        ph[0] = __floats2half2_rn(s * a0, s * a1);
        ph[1] = __floats2half2_rn(s * a2, s * a3);
        ph[2] = __floats2half2_rn(s * a4, s * a5);
        ph[3] = __floats2half2_rn(s * a6, s * a7);
        pack = *(const f32x4*)ph;
        __builtin_nontemporal_store(pack, (f32x4*)y_out + (size_t)wave * 4 + q);
    }
}

// out = 0.25*(emb + rdinv*(y1+y2+y3)); one thread per 8-elem chunk
__global__ __launch_bounds__(256) void final_kernel(const float* __restrict__ user,
                                                    const float* __restrict__ item,
                                                    const float* __restrict__ rdinv,
                                                    const __half* __restrict__ y1A,
                                                    const __half* __restrict__ y1B,
                                                    const __half* __restrict__ y2A,
                                                    const __half* __restrict__ y2B,
                                                    const __half* __restrict__ y3A,
                                                    const __half* __restrict__ y3B,
                                                    float* __restrict__ out,
                                                    int nU, int nN) {
    int c = blockIdx.x * blockDim.x + threadIdx.x;
    if (c >= nN * 8) return;
    int node = c >> 3;
    int qc = c & 7;
    float rd = 0.25f * rdinv[node];
    size_t hidx = (size_t)node * 4 + (qc & 3);
    const __half* t1 = (qc < 4) ? y1A : y1B;
    const __half* t2 = (qc < 4) ? y2A : y2B;
    const __half* t3 = (qc < 4) ? y3A : y3B;
    float4 h1 = ((const float4*)t1)[hidx];
    float4 h2 = ((const float4*)t2)[hidx];
    float4 h3 = ((const float4*)t3)[hidx];
    const float* src = (node < nU) ? user + (size_t)node * DIM
                                   : item + (size_t)(node - nU) * DIM;
    float4 e0 = ((const float4*)src)[qc * 2];
    float4 e1 = ((const float4*)src)[qc * 2 + 1];
    const __half2* p1 = (const __half2*)&h1;
    const __half2* p2 = (const __half2*)&h2;
    const __half2* p3 = (const __half2*)&h3;
    float r[8];
#pragma unroll
    for (int j = 0; j < 4; ++j) {
        float2 u1 = __half22float2(p1[j]);
        float2 u2 = __half22float2(p2[j]);
        float2 u3 = __half22float2(p3[j]);
        r[2 * j]     = u1.x + u2.x + u3.x;
        r[2 * j + 1] = u1.y + u2.y + u3.y;
    }
    float4 o0, o1;
    o0.x = 0.25f * e0.x + rd * r[0];
    o0.y = 0.25f * e0.y + rd * r[1];
    o0.z = 0.25f * e0.z + rd * r[2];
    o0.w = 0.25f * e0.w + rd * r[3];
    o1.x = 0.25f * e1.x + rd * r[4];
    o1.y = 0.25f * e1.y + rd * r[5];
    o1.z = 0.25f * e1.z + rd * r[6];
    o1.w = 0.25f * e1.w + rd * r[7];
    ((float4*)out)[(size_t)c * 2]     = o0;
    ((float4*)out)[(size_t)c * 2 + 1] = o1;
}

// ---------------- host launcher ----------------

extern "C" void kernel_launch(void* const* d_in, const int* in_sizes, int n_in,
                              void* d_out, int out_size, void* d_ws, size_t ws_size,
                              hipStream_t stream) {
    const float* user = (const float*)d_in[0];
    const float* item = (const float*)d_in[1];
    const int*   edge = (const int*)d_in[2];

    const int nU = in_sizes[0] / DIM;
    const int nI = in_sizes[1] / DIM;
    const int nN = nU + nI;
    const int E  = in_sizes[2] / 2;
    const int NB = (nN + 255) / 256;     // 256-node coarse buckets

    float* out = (float*)d_out;

    // workspace carve-up (256B aligned)
    char* ws = (char*)d_ws;
    size_t off = 0;
    auto take = [&](size_t bytes) -> char* {
        char* p = ws + off;
        off = (off + bytes + 255) & ~(size_t)255;
        return p;
    };
    const size_t hbytes = (size_t)nN * HDIM * 2;   // one half-table (fp16)
    const size_t binbytes = (size_t)E * 4;
    int*      bcnt       = (int*)  take((size_t)NB * 4);
    int*      boff       = (int*)  take((size_t)(NB + 1) * 4);
    int*      bcur       = (int*)  take((size_t)NB * 4);
    int*      offsets    = (int*)  take((size_t)(nN + 1) * 4);
    float*    dinv       = (float*)take((size_t)nN * 4);
    float*    rdinv      = (float*)take((size_t)nN * 4);
    int*      row_sorted = (int*)  take((size_t)E * 4);
    char*     R1 = take(binbytes > 2 * hbytes ? binbytes : 2 * hbytes); // bin, then y1A|y1B
    char*     R2 = take(2 * hbytes);                                    // y0A|y0B, then y3A|y3B
    char*     R3 = take(2 * hbytes);                                    // y2A|y2B
    unsigned* bin = (unsigned*)R1;
    __half*   y1A = (__half*)R1;
    __half*   y1B = (__half*)(R1 + hbytes);
    __half*   y0A = (__half*)R2;
    __half*   y0B = (__half*)(R2 + hbytes);
    __half*   y3A = y0A;
    __half*   y3B = y0B;
    __half*   y2A = (__half*)R3;
    __half*   y2B = (__half*)(R3 + hbytes);
    (void)ws_size; (void)n_in; (void)out_size;

    const int B = 256;
    dim3 blk(B);

    // 1. zero bucket counts
    zero_ints<<<dim3((NB + B - 1) / B), blk, 0, stream>>>(bcnt, NB);
    // 2. bucket histogram (LDS-aggregated)
    bucket_count_kernel<<<dim3(256), dim3(1024), 0, stream>>>(edge, E, bcnt, NB);
    // 3. bucket scan
    scan_kernel<<<dim3(1), dim3(1024), 0, stream>>>(bcnt, boff, bcur, NB);
    // 4. LDS-staged scatter into bucket-sorted bin
    bin_kernel<<<dim3((E + BINC - 1) / BINC), dim3(1024), 0, stream>>>(edge, E, bcur, bin, NB);
    // 5. per-bucket counting sort -> CSR + offsets + dinv/rdinv + fused split y0 init
    csr_kernel<<<dim3(NB), blk, 0, stream>>>(bin, boff, user, item, nU,
                                             offsets, dinv, rdinv, row_sorted, y0A, y0B, nN);

    // 6. three layers x two half-dim passes (9.6MB table per pass)
    dim3 lgrid((nN + 3) / 4);   // 4 waves (nodes) per 256-thread block
    layer_pass_kernel<<<lgrid, blk, 0, stream>>>(offsets, row_sorted, dinv, y0A, y1A, nN);
    layer_pass_kernel<<<lgrid, blk, 0, stream>>>(offsets, row_sorted, dinv, y0B, y1B, nN);
    layer_pass_kernel<<<lgrid, blk, 0, stream>>>(offsets, row_sorted, dinv, y1A, y2A, nN);
    layer_pass_kernel<<<lgrid, blk, 0, stream>>>(offsets, row_sorted, dinv, y1B, y2B, nN);
    layer_pass_kernel<<<lgrid, blk, 0, stream>>>(offsets, row_sorted, dinv, y2A, y3A, nN);
    layer_pass_kernel<<<lgrid, blk, 0, stream>>>(offsets, row_sorted, dinv, y2B, y3B, nN);

    // 7. streaming combine: out = 0.25*(emb + rdinv*(y1+y2+y3))
    final_kernel<<<dim3((nN * 8 + B - 1) / B), blk, 0, stream>>>(user, item, rdinv,
                                                                 y1A, y1B, y2A, y2B, y3A, y3B,
                                                                 out, nU, nN);
}

// Round 8
// 368.496 us; speedup vs baseline: 1.2980x; 1.2980x over previous
//
#include <hip/hip_runtime.h>
#include <hip/hip_fp16.h>

#define DIM 64
#define BSH 8                 // log2(nodes per bucket) = 256 nodes/bucket
#define BMASK 255u
#define NBMAX 1024            // max coarse buckets supported
#define BINC 16384            // edges staged per bin block
#define PADSTRIDE 4096        // max pad slots per bucket (256 nodes * 15 < 4096)

typedef __attribute__((ext_vector_type(4))) float f32x4;

// ---------------- prep kernels ----------------

__global__ void zero_ints(int* __restrict__ p, int n) {
    int i = blockIdx.x * blockDim.x + threadIdx.x;
    if (i < n) p[i] = 0;
}

// per-block LDS histogram of edges per coarse bucket
__global__ __launch_bounds__(1024) void bucket_count_kernel(const int* __restrict__ edge, int E,
                                                            int* __restrict__ bcnt, int NB) {
    __shared__ int lcnt[NBMAX];
    for (int i = threadIdx.x; i < NB; i += 1024) lcnt[i] = 0;
    __syncthreads();
    int stride = gridDim.x * 1024;
    for (int i = blockIdx.x * 1024 + threadIdx.x; i < E; i += stride)
        atomicAdd(&lcnt[edge[E + i] >> BSH], 1);
    __syncthreads();
    for (int i = threadIdx.x; i < NB; i += 1024) {
        int v = lcnt[i];
        if (v) atomicAdd(&bcnt[i], v);
    }
}

// single-block exclusive scan over n counts -> offsets[0..n], cursor copy
__global__ __launch_bounds__(1024) void scan_kernel(const int* __restrict__ cnt,
                                                    int* __restrict__ offsets,
                                                    int* __restrict__ cursor,
                                                    int n) {
    __shared__ int lds[1024];
    const int T = 1024, K = 4, CHUNK = T * K;
    int carry = 0;
    for (int base = 0; base < n; base += CHUNK) {
        int v[K];
        int idx0 = base + (int)threadIdx.x * K;
#pragma unroll
        for (int k = 0; k < K; ++k) {
            int i = idx0 + k;
            v[k] = (i < n) ? cnt[i] : 0;
        }
        int tsum = v[0] + v[1] + v[2] + v[3];
        lds[threadIdx.x] = tsum;
        __syncthreads();
        int incl = tsum;
        for (int off = 1; off < T; off <<= 1) {
            int t = (threadIdx.x >= (unsigned)off) ? lds[threadIdx.x - off] : 0;
            __syncthreads();
            incl += t;
            lds[threadIdx.x] = incl;
            __syncthreads();
        }
        int total = lds[T - 1];
        int run = carry + (incl - tsum);
#pragma unroll
        for (int k = 0; k < K; ++k) {
            int i = idx0 + k;
            if (i < n) { offsets[i] = run; cursor[i] = run; }
            run += v[k];
        }
        carry += total;
        __syncthreads();
    }
    if (threadIdx.x == 0) offsets[n] = carry;
}

// LDS-staged scatter into bucket-sorted bin; entry = (row << 8) | (col & 255)
__global__ __launch_bounds__(1024) void bin_kernel(const int* __restrict__ edge, int E,
                                                   int* __restrict__ bcur,
                                                   unsigned* __restrict__ bin, int NB) {
    __shared__ unsigned stage[BINC];
    __shared__ int lcnt[NBMAX];
    __shared__ int lsc[NBMAX];
    __shared__ int lcur[NBMAX];
    __shared__ int gb[NBMAX];
    const int tid = (int)threadIdx.x;
    const int beg = (int)blockIdx.x * BINC;
    const int n = min(BINC, E - beg);

    lcnt[tid] = 0;
    __syncthreads();
    for (int i = tid; i < n; i += 1024)
        atomicAdd(&lcnt[edge[E + beg + i] >> BSH], 1);
    __syncthreads();
    lsc[tid] = lcnt[tid];
    __syncthreads();
    for (int off = 1; off < 1024; off <<= 1) {
        int t = (tid >= off) ? lsc[tid - off] : 0;
        __syncthreads();
        lsc[tid] += t;
        __syncthreads();
    }
    {
        int cb = lcnt[tid];
        lcur[tid] = lsc[tid] - cb;
        if (tid < NB) gb[tid] = cb ? atomicAdd(&bcur[tid], cb) : 0;
    }
    __syncthreads();
    for (int i = tid; i < n; i += 1024) {
        int r = edge[beg + i];
        int c = edge[E + beg + i];
        int b = c >> BSH;
        int slot = atomicAdd(&lcur[b], 1);
        stage[slot] = ((unsigned)r << BSH) | ((unsigned)c & BMASK);
    }
    __syncthreads();
    const int wid = tid >> 6, lane = tid & 63;
    for (int b = wid; b < NB; b += 16) {
        int cb = lcnt[b];
        if (!cb) continue;
        int lb = lsc[b] - cb;
        int g = gb[b];
        for (int l = lane; l < cb; l += 64)
            bin[g + l] = stage[lb + l];
    }
}

// per-bucket counting sort -> PADDED CSR (+ zero-row pad), dinv/rdinv,
// fused y0 init (y0 = fp16(dinv * emb), full 128B rows)
__global__ __launch_bounds__(256) void csr_kernel(const unsigned* __restrict__ bin,
                                                  const int* __restrict__ boff,
                                                  const float* __restrict__ user,
                                                  const float* __restrict__ item,
                                                  int nU,
                                                  int* __restrict__ poff,
                                                  int* __restrict__ pcnt,
                                                  float* __restrict__ dinv,
                                                  float* __restrict__ rdinv,
                                                  int* __restrict__ row_padded,
                                                  __half* __restrict__ y0,
                                                  int nN) {
    __shared__ int lcnt[256];
    __shared__ int lps[256];
    __shared__ int lcur[256];
    __shared__ int spbeg[256];
    __shared__ float sdinv[256];
    const int tid = (int)threadIdx.x;
    const int b = (int)blockIdx.x;
    const int beg = boff[b], end = boff[b + 1];
    lcnt[tid] = 0;
    __syncthreads();
    for (int i = beg + tid; i < end; i += 256)
        atomicAdd(&lcnt[bin[i] & BMASK], 1);
    __syncthreads();
    const int cb = lcnt[tid];
    const int pc = (cb + 15) & ~15;      // padded count (multiple of 16)
    lps[tid] = pc;
    __syncthreads();
    for (int off = 1; off < 256; off <<= 1) {
        int t = (tid >= off) ? lps[tid - off] : 0;
        __syncthreads();
        lps[tid] += t;
        __syncthreads();
    }
    const int pbase = beg + b * PADSTRIDE;
    const int pbeg = pbase + (lps[tid] - pc);
    spbeg[tid] = pbeg;
    lcur[tid] = pbeg;
    float dv = cb ? rsqrtf((float)cb) : 0.0f;
    sdinv[tid] = dv;
    int node = (b << BSH) + tid;
    if (node < nN) {
        poff[node] = pbeg;
        pcnt[node] = pc;
        dinv[node] = dv;
        rdinv[node] = cb ? sqrtf((float)cb) : 0.0f;
    }
    __syncthreads();
    // scatter real edges to padded positions
    for (int i = beg + tid; i < end; i += 256) {
        unsigned e = bin[i];
        int c = (int)(e & BMASK);
        int p = atomicAdd(&lcur[c], 1);
        row_padded[p] = (int)(e >> BSH);
    }
    // fill pad slots with the zero-row index (nN)
    for (int k = cb; k < pc; ++k)
        row_padded[spbeg[tid] + k] = nN;
    // fused y0 init: 256 nodes x 8 chunks; chunk qc covers dims 8qc..8qc+7
    const int baseNode = b << BSH;
#pragma unroll
    for (int it = 0; it < 8; ++it) {
        int idx = it * 256 + tid;
        int ln = idx >> 3;
        int node2 = baseNode + ln;
        if (node2 < nN) {
            int qc = idx & 7;
            const float* src = (node2 < nU) ? user + (size_t)node2 * DIM
                                            : item + (size_t)(node2 - nU) * DIM;
            float4 e0 = ((const float4*)src)[qc * 2];
            float4 e1 = ((const float4*)src)[qc * 2 + 1];
            float dvn = sdinv[ln];
            float4 pack;
            __half2* p = (__half2*)&pack;
            p[0] = __floats2half2_rn(dvn * e0.x, dvn * e0.y);
            p[1] = __floats2half2_rn(dvn * e0.z, dvn * e0.w);
            p[2] = __floats2half2_rn(dvn * e1.x, dvn * e1.y);
            p[3] = __floats2half2_rn(dvn * e1.z, dvn * e1.w);
            ((float4*)y0)[(size_t)baseNode * 8 + idx] = pack;
        }
    }
}

// zero the pad row (row nN) of the three y regions
__global__ void zero_row_kernel(__half* __restrict__ r1, __half* __restrict__ r2,
                                __half* __restrict__ r3, int nN) {
    int t = threadIdx.x;       // 64 threads
    size_t o = (size_t)nN * DIM + t;
    r1[o] = __float2half(0.0f);
    r2[o] = __float2half(0.0f);
    r3[o] = __float2half(0.0f);
}

// one wave per node; 8 edge-slots x 8 lanes; lane loads float4 (8 halves);
// 16 edges (2KB) in flight; padded edge list -> branchless/maskless body.
__global__ __launch_bounds__(256) void layer_kernel(const int* __restrict__ poff,
                                                    const int* __restrict__ pcnt,
                                                    const float* __restrict__ dinv,
                                                    const int* __restrict__ row_padded,
                                                    const __half* __restrict__ y_in,
                                                    __half* __restrict__ y_out,
                                                    int nN) {
    int wave = (int)((blockIdx.x * blockDim.x + threadIdx.x) >> 6);
    int lane = (int)(threadIdx.x & 63);
    if (wave >= nN) return;
    const int beg = poff[wave];
    const int n = pcnt[wave];
    const int g = lane >> 3;   // edge slot 0..7
    const int q = lane & 7;    // 16B chunk of the row, 0..7
    const float4* yv = (const float4*)y_in;
    float a0 = 0, a1 = 0, a2 = 0, a3 = 0, a4 = 0, a5 = 0, a6 = 0, a7 = 0;
    for (int base = 0; base < n; base += 16) {
        int e0 = beg + base + g;
        int r0 = __builtin_nontemporal_load(row_padded + e0);
        int r1 = __builtin_nontemporal_load(row_padded + e0 + 8);
        float4 v0 = yv[(size_t)r0 * 8 + q];
        float4 v1 = yv[(size_t)r1 * 8 + q];
        const __half2* h0 = (const __half2*)&v0;
        const __half2* h1 = (const __half2*)&v1;
        float2 t;
        t = __half22float2(h0[0]); a0 += t.x; a1 += t.y;
        t = __half22float2(h0[1]); a2 += t.x; a3 += t.y;
        t = __half22float2(h0[2]); a4 += t.x; a5 += t.y;
        t = __half22float2(h0[3]); a6 += t.x; a7 += t.y;
        t = __half22float2(h1[0]); a0 += t.x; a1 += t.y;
        t = __half22float2(h1[1]); a2 += t.x; a3 += t.y;
        t = __half22float2(h1[2]); a4 += t.x; a5 += t.y;
        t = __half22float2(h1[3]); a6 += t.x; a7 += t.y;
    }
    // reduce across the 8 edge-slots (lane bits 3..5)
#pragma unroll
    for (int ofs = 8; ofs <= 32; ofs <<= 1) {
        a0 += __shfl_xor(a0, ofs);
        a1 += __shfl_xor(a1, ofs);
        a2 += __shfl_xor(a2, ofs);
        a3 += __shfl_xor(a3, ofs);
        a4 += __shfl_xor(a4, ofs);
        a5 += __shfl_xor(a5, ofs);
        a6 += __shfl_xor(a6, ofs);
        a7 += __shfl_xor(a7, ofs);
    }
    if (g == 0) {
        float dc = dinv[wave];
        float s = dc * dc;          // y_out = dinv * (dinv * sum)
        __half2 ph[4];
        ph[0] = __floats2half2_rn(s * a0, s * a1);
        ph[1] = __floats2half2_rn(s * a2, s * a3);
        ph[2] = __floats2half2_rn(s * a4, s * a5);
        ph[3] = __floats2half2_rn(s * a6, s * a7);
        f32x4 pack = *(const f32x4*)ph;
        __builtin_nontemporal_store(pack, (f32x4*)y_out + (size_t)wave * 8 + q);
    }
}

// out = 0.25*(emb + rdinv*(y1+y2+y3)); one thread per 8-elem chunk
__global__ __launch_bounds__(256) void final_kernel(const float* __restrict__ user,
                                                    const float* __restrict__ item,
                                                    const float* __restrict__ rdinv,
                                                    const __half* __restrict__ y1,
                                                    const __half* __restrict__ y2,
                                                    const __half* __restrict__ y3,
                                                    float* __restrict__ out,
                                                    int nU, int nN) {
    int c = blockIdx.x * blockDim.x + threadIdx.x;
    if (c >= nN * 8) return;
    int node = c >> 3;
    int qc = c & 7;
    float rd = 0.25f * rdinv[node];
    float4 h1 = ((const float4*)y1)[c];
    float4 h2 = ((const float4*)y2)[c];
    float4 h3 = ((const float4*)y3)[c];
    const float* src = (node < nU) ? user + (size_t)node * DIM
                                   : item + (size_t)(node - nU) * DIM;
    float4 e0 = ((const float4*)src)[qc * 2];
    float4 e1 = ((const float4*)src)[qc * 2 + 1];
    const __half2* p1 = (const __half2*)&h1;
    const __half2* p2 = (const __half2*)&h2;
    const __half2* p3 = (const __half2*)&h3;
    float r[8];
#pragma unroll
    for (int j = 0; j < 4; ++j) {
        float2 u1 = __half22float2(p1[j]);
        float2 u2 = __half22float2(p2[j]);
        float2 u3 = __half22float2(p3[j]);
        r[2 * j]     = u1.x + u2.x + u3.x;
        r[2 * j + 1] = u1.y + u2.y + u3.y;
    }
    float4 o0, o1;
    o0.x = 0.25f * e0.x + rd * r[0];
    o0.y = 0.25f * e0.y + rd * r[1];
    o0.z = 0.25f * e0.z + rd * r[2];
    o0.w = 0.25f * e0.w + rd * r[3];
    o1.x = 0.25f * e1.x + rd * r[4];
    o1.y = 0.25f * e1.y + rd * r[5];
    o1.z = 0.25f * e1.z + rd * r[6];
    o1.w = 0.25f * e1.w + rd * r[7];
    ((float4*)out)[(size_t)c * 2]     = o0;
    ((float4*)out)[(size_t)c * 2 + 1] = o1;
}

// ---------------- host launcher ----------------

extern "C" void kernel_launch(void* const* d_in, const int* in_sizes, int n_in,
                              void* d_out, int out_size, void* d_ws, size_t ws_size,
                              hipStream_t stream) {
    const float* user = (const float*)d_in[0];
    const float* item = (const float*)d_in[1];
    const int*   edge = (const int*)d_in[2];

    const int nU = in_sizes[0] / DIM;
    const int nI = in_sizes[1] / DIM;
    const int nN = nU + nI;
    const int E  = in_sizes[2] / 2;
    const int NB = (nN + 255) / 256;     // 256-node coarse buckets

    float* out = (float*)d_out;

    // workspace carve-up (256B aligned)
    char* ws = (char*)d_ws;
    size_t off = 0;
    auto take = [&](size_t bytes) -> char* {
        char* p = ws + off;
        off = (off + bytes + 255) & ~(size_t)255;
        return p;
    };
    const size_t ytab = (size_t)(nN + 1) * DIM * 2;       // fp16 table incl. zero row
    const size_t binbytes = (size_t)E * 4;
    const size_t padbytes = ((size_t)E + (size_t)NB * PADSTRIDE) * 4;
    int*      bcnt       = (int*)  take((size_t)NB * 4);
    int*      boff       = (int*)  take((size_t)(NB + 1) * 4);
    int*      bcur       = (int*)  take((size_t)NB * 4);
    int*      poff       = (int*)  take((size_t)nN * 4);
    int*      pcnt       = (int*)  take((size_t)nN * 4);
    float*    dinv       = (float*)take((size_t)nN * 4);
    float*    rdinv      = (float*)take((size_t)nN * 4);
    int*      row_padded = (int*)  take(padbytes);
    char*     R1 = take(binbytes > ytab ? binbytes : ytab);  // bin, then y1
    char*     R2 = take(ytab);                               // y0, then y3
    char*     R3 = take(ytab);                               // y2
    unsigned* bin = (unsigned*)R1;
    __half*   y1  = (__half*)R1;
    __half*   y0  = (__half*)R2;
    __half*   y3  = (__half*)R2;
    __half*   y2  = (__half*)R3;
    (void)ws_size; (void)n_in; (void)out_size;

    const int B = 256;
    dim3 blk(B);

    // 1. zero bucket counts
    zero_ints<<<dim3((NB + B - 1) / B), blk, 0, stream>>>(bcnt, NB);
    // 2. bucket histogram (LDS-aggregated)
    bucket_count_kernel<<<dim3(256), dim3(1024), 0, stream>>>(edge, E, bcnt, NB);
    // 3. bucket scan
    scan_kernel<<<dim3(1), dim3(1024), 0, stream>>>(bcnt, boff, bcur, NB);
    // 4. LDS-staged scatter into bucket-sorted bin
    bin_kernel<<<dim3((E + BINC - 1) / BINC), dim3(1024), 0, stream>>>(edge, E, bcur, bin, NB);
    // 5. per-bucket counting sort -> padded CSR + dinv/rdinv + fused y0 init
    csr_kernel<<<dim3(NB), blk, 0, stream>>>(bin, boff, user, item, nU,
                                             poff, pcnt, dinv, rdinv, row_padded, y0, nN);
    // 5b. zero the pad row of all three y regions (after bin is consumed)
    zero_row_kernel<<<dim3(1), dim3(64), 0, stream>>>(y1, y0, y2, nN);

    // 6. three propagation layers (wave per node, padded branchless gathers)
    dim3 lgrid((nN + 3) / 4);   // 4 waves (nodes) per 256-thread block
    layer_kernel<<<lgrid, blk, 0, stream>>>(poff, pcnt, dinv, row_padded, y0, y1, nN);
    layer_kernel<<<lgrid, blk, 0, stream>>>(poff, pcnt, dinv, row_padded, y1, y2, nN);
    layer_kernel<<<lgrid, blk, 0, stream>>>(poff, pcnt, dinv, row_padded, y2, y3, nN);

    // 7. streaming combine: out = 0.25*(emb + rdinv*(y1+y2+y3))
    final_kernel<<<dim3((nN * 8 + B - 1) / B), blk, 0, stream>>>(user, item, rdinv,
                                                                 y1, y2, y3, out, nU, nN);
}

// Round 9
// 341.147 us; speedup vs baseline: 1.4021x; 1.0802x over previous
//
#include <hip/hip_runtime.h>
#include <hip/hip_fp16.h>

#define DIM 64
#define BSH 8                 // log2(nodes per bucket) = 256 nodes/bucket
#define BMASK 255u
#define NBMAX 1024            // max coarse buckets supported
#define BINC 16384            // edges staged per bin block
#define BSTRIDE 8192          // fixed arena per bucket (avg 6826, >10 sigma margin)

typedef __attribute__((ext_vector_type(4))) float f32x4;

// ---------------- prep kernels ----------------

__global__ void zero_ints(int* __restrict__ p, int n) {
    int i = blockIdx.x * blockDim.x + threadIdx.x;
    if (i < n) p[i] = 0;
}

// LDS-staged scatter into fixed-stride bucket arenas; entry = (row<<8)|(col&255).
// Reserves one contiguous range per (block,bucket) with a single global atomic.
__global__ __launch_bounds__(1024) void bin_kernel(const int* __restrict__ edge, int E,
                                                   int* __restrict__ bcur,
                                                   unsigned* __restrict__ bin, int NB) {
    __shared__ unsigned stage[BINC];
    __shared__ int lcnt[NBMAX];
    __shared__ int lsc[NBMAX];
    __shared__ int lcur[NBMAX];
    __shared__ int gb[NBMAX];
    const int tid = (int)threadIdx.x;
    const int beg = (int)blockIdx.x * BINC;
    const int n = min(BINC, E - beg);

    lcnt[tid] = 0;
    __syncthreads();
    // phase 1: count per bucket
    for (int i = tid; i < n; i += 1024)
        atomicAdd(&lcnt[edge[E + beg + i] >> BSH], 1);
    __syncthreads();
    // inclusive scan over 1024 slots
    lsc[tid] = lcnt[tid];
    __syncthreads();
    for (int off = 1; off < 1024; off <<= 1) {
        int t = (tid >= off) ? lsc[tid - off] : 0;
        __syncthreads();
        lsc[tid] += t;
        __syncthreads();
    }
    // reserve per-bucket global ranges (fixed-stride arenas)
    {
        int cb = lcnt[tid];
        lcur[tid] = lsc[tid] - cb;
        if (tid < NB) gb[tid] = cb ? atomicAdd(&bcur[tid], cb) : 0;
    }
    __syncthreads();
    // phase 2: rank into LDS stage (sorted by bucket)
    for (int i = tid; i < n; i += 1024) {
        int r = edge[beg + i];
        int c = edge[E + beg + i];
        int b = c >> BSH;
        int slot = atomicAdd(&lcur[b], 1);
        stage[slot] = ((unsigned)r << BSH) | ((unsigned)c & BMASK);
    }
    __syncthreads();
    // phase 3: per-bucket coalesced copy out into the bucket arena
    const int wid = tid >> 6, lane = tid & 63;
    for (int b = wid; b < NB; b += 16) {
        int cb = lcnt[b];
        if (!cb) continue;
        int lb = lsc[b] - cb;
        int g = b * BSTRIDE + gb[b];
        for (int l = lane; l < cb; l += 64)
            bin[g + l] = stage[lb + l];
    }
}

// per-bucket counting sort -> CSR (fixed-stride arena) + poff/pdeg + dinv/rdinv,
// fused y0 init (y0 = fp16(dinv * emb))
__global__ __launch_bounds__(256) void csr_kernel(const unsigned* __restrict__ bin,
                                                  const int* __restrict__ bcnt,
                                                  const float* __restrict__ user,
                                                  const float* __restrict__ item,
                                                  int nU,
                                                  int* __restrict__ poff,
                                                  int* __restrict__ pdeg,
                                                  float* __restrict__ dinv,
                                                  float* __restrict__ rdinv,
                                                  int* __restrict__ row_sorted,
                                                  __half* __restrict__ y0,
                                                  int nN) {
    __shared__ int lcnt[256];
    __shared__ int lsc[256];
    __shared__ int lcur[256];
    __shared__ float sdinv[256];
    const int tid = (int)threadIdx.x;
    const int b = (int)blockIdx.x;
    const int abase = b * BSTRIDE;
    const int cnt = bcnt[b];
    lcnt[tid] = 0;
    __syncthreads();
    for (int i = tid; i < cnt; i += 256)
        atomicAdd(&lcnt[bin[abase + i] & BMASK], 1);
    __syncthreads();
    lsc[tid] = lcnt[tid];
    __syncthreads();
    for (int off = 1; off < 256; off <<= 1) {
        int t = (tid >= off) ? lsc[tid - off] : 0;
        __syncthreads();
        lsc[tid] += t;
        __syncthreads();
    }
    const int cb = lcnt[tid];
    const int lb = lsc[tid] - cb;
    lcur[tid] = abase + lb;
    float dv = cb ? rsqrtf((float)cb) : 0.0f;
    sdinv[tid] = dv;
    int node = (b << BSH) + tid;
    if (node < nN) {
        poff[node] = abase + lb;
        pdeg[node] = cb;
        dinv[node] = dv;
        rdinv[node] = cb ? sqrtf((float)cb) : 0.0f;
    }
    __syncthreads();
    for (int i = tid; i < cnt; i += 256) {
        unsigned e = bin[abase + i];
        int c = (int)(e & BMASK);
        int p = atomicAdd(&lcur[c], 1);
        row_sorted[p] = (int)(e >> BSH);
    }
    // fused y0 init: 256 nodes x 8 chunks; chunk qc covers dims 8qc..8qc+7
    const int baseNode = b << BSH;
#pragma unroll
    for (int it = 0; it < 8; ++it) {
        int idx = it * 256 + tid;
        int ln = idx >> 3;
        int node2 = baseNode + ln;
        if (node2 < nN) {
            int qc = idx & 7;
            const float* src = (node2 < nU) ? user + (size_t)node2 * DIM
                                            : item + (size_t)(node2 - nU) * DIM;
            float4 e0 = ((const float4*)src)[qc * 2];
            float4 e1 = ((const float4*)src)[qc * 2 + 1];
            float dvn = sdinv[ln];
            float4 pack;
            __half2* p = (__half2*)&pack;
            p[0] = __floats2half2_rn(dvn * e0.x, dvn * e0.y);
            p[1] = __floats2half2_rn(dvn * e0.z, dvn * e0.w);
            p[2] = __floats2half2_rn(dvn * e1.x, dvn * e1.y);
            p[3] = __floats2half2_rn(dvn * e1.z, dvn * e1.w);
            ((float4*)y0)[(size_t)baseNode * 8 + idx] = pack;
        }
    }
}

// one wave per node; 8 edge-slots x 8 lanes; lane loads float4 (8 halves);
// 16 edges (2KB) in flight; masked tail (no padding - pads cost like real gathers).
// LAST fuses the final combine: out = 0.25*(emb + rdinv*(y1+y2) + dinv*sum).
template<bool LAST>
__global__ __launch_bounds__(256) void layer_kernel(const int* __restrict__ poff,
                                                    const int* __restrict__ pdeg,
                                                    const float* __restrict__ dinv,
                                                    const int* __restrict__ row_sorted,
                                                    const __half* __restrict__ y_in,
                                                    __half* __restrict__ y_out,
                                                    const float* __restrict__ user,
                                                    const float* __restrict__ item,
                                                    const float* __restrict__ rdinv,
                                                    const __half* __restrict__ y_prev,
                                                    float* __restrict__ out,
                                                    int nU, int nN) {
    int wave = (int)((blockIdx.x * blockDim.x + threadIdx.x) >> 6);
    int lane = (int)(threadIdx.x & 63);
    if (wave >= nN) return;
    const int beg = poff[wave];
    const int end = beg + pdeg[wave];
    const int g = lane >> 3;   // edge slot 0..7
    const int q = lane & 7;    // 16B chunk of the row, 0..7
    const float4* yv = (const float4*)y_in;
    float a0 = 0, a1 = 0, a2 = 0, a3 = 0, a4 = 0, a5 = 0, a6 = 0, a7 = 0;
    const int last = end - 1;
    for (int base = beg; base < end; base += 16) {
        int e0 = base + g;
        int e1 = e0 + 8;
        int i0 = (e0 <= last) ? e0 : last;
        int i1 = (e1 <= last) ? e1 : last;
        float m0 = (e0 <= last) ? 1.0f : 0.0f;
        float m1 = (e1 <= last) ? 1.0f : 0.0f;
        int r0 = __builtin_nontemporal_load(row_sorted + i0);
        int r1 = __builtin_nontemporal_load(row_sorted + i1);
        float4 v0 = yv[(size_t)r0 * 8 + q];
        float4 v1 = yv[(size_t)r1 * 8 + q];
        const __half2* h0 = (const __half2*)&v0;
        const __half2* h1 = (const __half2*)&v1;
        float2 t;
        t = __half22float2(h0[0]); a0 = fmaf(m0, t.x, a0); a1 = fmaf(m0, t.y, a1);
        t = __half22float2(h0[1]); a2 = fmaf(m0, t.x, a2); a3 = fmaf(m0, t.y, a3);
        t = __half22float2(h0[2]); a4 = fmaf(m0, t.x, a4); a5 = fmaf(m0, t.y, a5);
        t = __half22float2(h0[3]); a6 = fmaf(m0, t.x, a6); a7 = fmaf(m0, t.y, a7);
        t = __half22float2(h1[0]); a0 = fmaf(m1, t.x, a0); a1 = fmaf(m1, t.y, a1);
        t = __half22float2(h1[1]); a2 = fmaf(m1, t.x, a2); a3 = fmaf(m1, t.y, a3);
        t = __half22float2(h1[2]); a4 = fmaf(m1, t.x, a4); a5 = fmaf(m1, t.y, a5);
        t = __half22float2(h1[3]); a6 = fmaf(m1, t.x, a6); a7 = fmaf(m1, t.y, a7);
    }
    // reduce across the 8 edge-slots (lane bits 3..5)
#pragma unroll
    for (int ofs = 8; ofs <= 32; ofs <<= 1) {
        a0 += __shfl_xor(a0, ofs);
        a1 += __shfl_xor(a1, ofs);
        a2 += __shfl_xor(a2, ofs);
        a3 += __shfl_xor(a3, ofs);
        a4 += __shfl_xor(a4, ofs);
        a5 += __shfl_xor(a5, ofs);
        a6 += __shfl_xor(a6, ofs);
        a7 += __shfl_xor(a7, ofs);
    }
    if (g == 0) {
        float dc = dinv[wave];
        if (!LAST) {
            float s = dc * dc;          // y_out = dinv * (dinv * sum)
            __half2 ph[4];
            ph[0] = __floats2half2_rn(s * a0, s * a1);
            ph[1] = __floats2half2_rn(s * a2, s * a3);
            ph[2] = __floats2half2_rn(s * a4, s * a5);
            ph[3] = __floats2half2_rn(s * a6, s * a7);
            f32x4 pack = *(const f32x4*)ph;
            __builtin_nontemporal_store(pack, (f32x4*)y_out + (size_t)wave * 8 + q);
        } else {
            // out = 0.25*(emb + rdinv*(y1+y2) + dinv*sum)
            float rd = rdinv[wave];
            float4 y1r = ((const float4*)y_prev)[(size_t)wave * 8 + q];
            float4 y2r = ((const float4*)y_in)[(size_t)wave * 8 + q];
            const __half2* p1 = (const __half2*)&y1r;
            const __half2* p2 = (const __half2*)&y2r;
            float w[8];
#pragma unroll
            for (int j = 0; j < 4; ++j) {
                float2 u1 = __half22float2(p1[j]);
                float2 u2 = __half22float2(p2[j]);
                w[2 * j]     = u1.x + u2.x;
                w[2 * j + 1] = u1.y + u2.y;
            }
            const float* src = (wave < nU) ? user + (size_t)wave * DIM
                                           : item + (size_t)(wave - nU) * DIM;
            float4 e0 = ((const float4*)src)[q * 2];
            float4 e1 = ((const float4*)src)[q * 2 + 1];
            float4 o0, o1;
            o0.x = 0.25f * (e0.x + rd * w[0] + dc * a0);
            o0.y = 0.25f * (e0.y + rd * w[1] + dc * a1);
            o0.z = 0.25f * (e0.z + rd * w[2] + dc * a2);
            o0.w = 0.25f * (e0.w + rd * w[3] + dc * a3);
            o1.x = 0.25f * (e1.x + rd * w[4] + dc * a4);
            o1.y = 0.25f * (e1.y + rd * w[5] + dc * a5);
            o1.z = 0.25f * (e1.z + rd * w[6] + dc * a6);
            o1.w = 0.25f * (e1.w + rd * w[7] + dc * a7);
            float4* o4 = (float4*)(out + (size_t)wave * DIM + q * 8);
            o4[0] = o0;
            o4[1] = o1;
        }
    }
}

// ---------------- host launcher ----------------

extern "C" void kernel_launch(void* const* d_in, const int* in_sizes, int n_in,
                              void* d_out, int out_size, void* d_ws, size_t ws_size,
                              hipStream_t stream) {
    const float* user = (const float*)d_in[0];
    const float* item = (const float*)d_in[1];
    const int*   edge = (const int*)d_in[2];

    const int nU = in_sizes[0] / DIM;
    const int nI = in_sizes[1] / DIM;
    const int nN = nU + nI;
    const int E  = in_sizes[2] / 2;
    const int NB = (nN + 255) / 256;     // 256-node coarse buckets

    float* out = (float*)d_out;

    // workspace carve-up (256B aligned)
    char* ws = (char*)d_ws;
    size_t off = 0;
    auto take = [&](size_t bytes) -> char* {
        char* p = ws + off;
        off = (off + bytes + 255) & ~(size_t)255;
        return p;
    };
    const size_t ytab = (size_t)nN * DIM * 2;            // fp16 table
    const size_t arena = (size_t)NB * BSTRIDE * 4;       // fixed-stride arena
    int*      bcur       = (int*)  take((size_t)NB * 4);
    int*      poff       = (int*)  take((size_t)nN * 4);
    int*      pdeg       = (int*)  take((size_t)nN * 4);
    float*    dinv       = (float*)take((size_t)nN * 4);
    float*    rdinv      = (float*)take((size_t)nN * 4);
    int*      row_sorted = (int*)  take(arena);
    char*     R1 = take(arena > ytab ? arena : ytab);    // bin, then y1
    char*     R2 = take(ytab);                           // y0
    char*     R3 = take(ytab);                           // y2
    unsigned* bin = (unsigned*)R1;
    __half*   y1  = (__half*)R1;
    __half*   y0  = (__half*)R2;
    __half*   y2  = (__half*)R3;
    (void)ws_size; (void)n_in; (void)out_size;

    const int B = 256;
    dim3 blk(B);

    // 1. zero bucket cursors
    zero_ints<<<dim3((NB + B - 1) / B), blk, 0, stream>>>(bcur, NB);
    // 2. LDS-staged scatter into fixed-stride bucket arenas
    bin_kernel<<<dim3((E + BINC - 1) / BINC), dim3(1024), 0, stream>>>(edge, E, bcur, bin, NB);
    // 3. per-bucket counting sort -> CSR + dinv/rdinv + fused y0 init
    csr_kernel<<<dim3(NB), blk, 0, stream>>>(bin, bcur, user, item, nU,
                                             poff, pdeg, dinv, rdinv, row_sorted, y0, nN);

    // 4. three propagation layers; layer 3 fuses the final combine
    dim3 lgrid((nN + 3) / 4);   // 4 waves (nodes) per 256-thread block
    layer_kernel<false><<<lgrid, blk, 0, stream>>>(poff, pdeg, dinv, row_sorted, y0, y1,
                                                   nullptr, nullptr, nullptr, nullptr, nullptr,
                                                   nU, nN);
    layer_kernel<false><<<lgrid, blk, 0, stream>>>(poff, pdeg, dinv, row_sorted, y1, y2,
                                                   nullptr, nullptr, nullptr, nullptr, nullptr,
                                                   nU, nN);
    layer_kernel<true ><<<lgrid, blk, 0, stream>>>(poff, pdeg, dinv, row_sorted, y2, nullptr,
                                                   user, item, rdinv, y1, out,
                                                   nU, nN);
}

// Round 10
// 300.184 us; speedup vs baseline: 1.5934x; 1.1365x over previous
//
#include <hip/hip_runtime.h>
#include <hip/hip_fp16.h>

#define DIM 64
#define BSH 8                 // log2(nodes per bucket) = 256 nodes/bucket
#define BMASK 255u
#define NBMAX 1024            // max coarse buckets supported
#define BINC 16384            // edges staged per bin block
#define BSTRIDE 8192          // fixed arena per bucket (avg 6826, >10 sigma margin)

// ---------------- prep kernels ----------------

__global__ void zero_ints(int* __restrict__ p, int n) {
    int i = blockIdx.x * blockDim.x + threadIdx.x;
    if (i < n) p[i] = 0;
}

// LDS-staged scatter into fixed-stride bucket arenas; entry = (row<<8)|(col&255).
// Reserves one contiguous range per (block,bucket) with a single global atomic.
__global__ __launch_bounds__(1024) void bin_kernel(const int* __restrict__ edge, int E,
                                                   int* __restrict__ bcur,
                                                   unsigned* __restrict__ bin, int NB) {
    __shared__ unsigned stage[BINC];
    __shared__ int lcnt[NBMAX];
    __shared__ int lsc[NBMAX];
    __shared__ int lcur[NBMAX];
    __shared__ int gb[NBMAX];
    const int tid = (int)threadIdx.x;
    const int beg = (int)blockIdx.x * BINC;
    const int n = min(BINC, E - beg);

    lcnt[tid] = 0;
    __syncthreads();
    // phase 1: count per bucket
    for (int i = tid; i < n; i += 1024)
        atomicAdd(&lcnt[edge[E + beg + i] >> BSH], 1);
    __syncthreads();
    // inclusive scan over 1024 slots
    lsc[tid] = lcnt[tid];
    __syncthreads();
    for (int off = 1; off < 1024; off <<= 1) {
        int t = (tid >= off) ? lsc[tid - off] : 0;
        __syncthreads();
        lsc[tid] += t;
        __syncthreads();
    }
    // reserve per-bucket global ranges (fixed-stride arenas)
    {
        int cb = lcnt[tid];
        lcur[tid] = lsc[tid] - cb;
        if (tid < NB) gb[tid] = cb ? atomicAdd(&bcur[tid], cb) : 0;
    }
    __syncthreads();
    // phase 2: rank into LDS stage (sorted by bucket)
    for (int i = tid; i < n; i += 1024) {
        int r = edge[beg + i];
        int c = edge[E + beg + i];
        int b = c >> BSH;
        int slot = atomicAdd(&lcur[b], 1);
        stage[slot] = ((unsigned)r << BSH) | ((unsigned)c & BMASK);
    }
    __syncthreads();
    // phase 3: per-bucket coalesced copy out into the bucket arena
    const int wid = tid >> 6, lane = tid & 63;
    for (int b = wid; b < NB; b += 16) {
        int cb = lcnt[b];
        if (!cb) continue;
        int lb = lsc[b] - cb;
        int g = b * BSTRIDE + gb[b];
        for (int l = lane; l < cb; l += 64)
            bin[g + l] = stage[lb + l];
    }
}

// per-bucket counting sort -> CSR (fixed-stride arena) + pdesc + dinv/rdinv,
// fused y0 init (y0 = fp16(dinv * emb))
__global__ __launch_bounds__(256) void csr_kernel(const unsigned* __restrict__ bin,
                                                  const int* __restrict__ bcnt,
                                                  const float* __restrict__ user,
                                                  const float* __restrict__ item,
                                                  int nU,
                                                  int2* __restrict__ pdesc,
                                                  float* __restrict__ dinv,
                                                  float* __restrict__ rdinv,
                                                  int* __restrict__ row_sorted,
                                                  __half* __restrict__ y0,
                                                  int nN) {
    __shared__ int lcnt[256];
    __shared__ int lsc[256];
    __shared__ int lcur[256];
    __shared__ float sdinv[256];
    const int tid = (int)threadIdx.x;
    const int b = (int)blockIdx.x;
    const int abase = b * BSTRIDE;
    const int cnt = bcnt[b];
    lcnt[tid] = 0;
    __syncthreads();
    for (int i = tid; i < cnt; i += 256)
        atomicAdd(&lcnt[bin[abase + i] & BMASK], 1);
    __syncthreads();
    lsc[tid] = lcnt[tid];
    __syncthreads();
    for (int off = 1; off < 256; off <<= 1) {
        int t = (tid >= off) ? lsc[tid - off] : 0;
        __syncthreads();
        lsc[tid] += t;
        __syncthreads();
    }
    const int cb = lcnt[tid];
    const int lb = lsc[tid] - cb;
    lcur[tid] = abase + lb;
    float dv = cb ? rsqrtf((float)cb) : 0.0f;
    sdinv[tid] = dv;
    int node = (b << BSH) + tid;
    if (node < nN) {
        pdesc[node] = make_int2(abase + lb, cb);
        dinv[node] = dv;
        rdinv[node] = cb ? sqrtf((float)cb) : 0.0f;
    }
    __syncthreads();
    for (int i = tid; i < cnt; i += 256) {
        unsigned e = bin[abase + i];
        int c = (int)(e & BMASK);
        int p = atomicAdd(&lcur[c], 1);
        row_sorted[p] = (int)(e >> BSH);
    }
    // fused y0 init: 256 nodes x 8 chunks; chunk qc covers dims 8qc..8qc+7
    const int baseNode = b << BSH;
#pragma unroll
    for (int it = 0; it < 8; ++it) {
        int idx = it * 256 + tid;
        int ln = idx >> 3;
        int node2 = baseNode + ln;
        if (node2 < nN) {
            int qc = idx & 7;
            const float* src = (node2 < nU) ? user + (size_t)node2 * DIM
                                            : item + (size_t)(node2 - nU) * DIM;
            float4 e0 = ((const float4*)src)[qc * 2];
            float4 e1 = ((const float4*)src)[qc * 2 + 1];
            float dvn = sdinv[ln];
            float4 pack;
            __half2* p = (__half2*)&pack;
            p[0] = __floats2half2_rn(dvn * e0.x, dvn * e0.y);
            p[1] = __floats2half2_rn(dvn * e0.z, dvn * e0.w);
            p[2] = __floats2half2_rn(dvn * e1.x, dvn * e1.y);
            p[3] = __floats2half2_rn(dvn * e1.z, dvn * e1.w);
            ((float4*)y0)[(size_t)baseNode * 8 + idx] = pack;
        }
    }
}

// one wave per node; 8 edge-slots x 8 lanes; lane loads float4 (8 halves);
// 16 edges (2KB) in flight; masked tail. Plain (cached) loads/stores.
// LAST fuses the final combine: out = 0.25*(emb + rdinv*(y1+y2) + dinv*sum).
template<bool LAST>
__global__ __launch_bounds__(256) void layer_kernel(const int2* __restrict__ pdesc,
                                                    const float* __restrict__ dinv,
                                                    const int* __restrict__ row_sorted,
                                                    const __half* __restrict__ y_in,
                                                    __half* __restrict__ y_out,
                                                    const float* __restrict__ user,
                                                    const float* __restrict__ item,
                                                    const float* __restrict__ rdinv,
                                                    const __half* __restrict__ y_prev,
                                                    float* __restrict__ out,
                                                    int nU, int nN) {
    int wave = (int)((blockIdx.x * blockDim.x + threadIdx.x) >> 6);
    int lane = (int)(threadIdx.x & 63);
    if (wave >= nN) return;
    const int2 pd = pdesc[wave];
    const int beg = pd.x;
    const int end = beg + pd.y;
    const int g = lane >> 3;   // edge slot 0..7
    const int q = lane & 7;    // 16B chunk of the row, 0..7
    const float4* yv = (const float4*)y_in;
    float a0 = 0, a1 = 0, a2 = 0, a3 = 0, a4 = 0, a5 = 0, a6 = 0, a7 = 0;
    const int last = end - 1;
    for (int base = beg; base < end; base += 16) {
        int e0 = base + g;
        int e1 = e0 + 8;
        int i0 = (e0 <= last) ? e0 : last;
        int i1 = (e1 <= last) ? e1 : last;
        float m0 = (e0 <= last) ? 1.0f : 0.0f;
        float m1 = (e1 <= last) ? 1.0f : 0.0f;
        int r0 = row_sorted[i0];
        int r1 = row_sorted[i1];
        float4 v0 = yv[(size_t)r0 * 8 + q];
        float4 v1 = yv[(size_t)r1 * 8 + q];
        const __half2* h0 = (const __half2*)&v0;
        const __half2* h1 = (const __half2*)&v1;
        float2 t;
        t = __half22float2(h0[0]); a0 = fmaf(m0, t.x, a0); a1 = fmaf(m0, t.y, a1);
        t = __half22float2(h0[1]); a2 = fmaf(m0, t.x, a2); a3 = fmaf(m0, t.y, a3);
        t = __half22float2(h0[2]); a4 = fmaf(m0, t.x, a4); a5 = fmaf(m0, t.y, a5);
        t = __half22float2(h0[3]); a6 = fmaf(m0, t.x, a6); a7 = fmaf(m0, t.y, a7);
        t = __half22float2(h1[0]); a0 = fmaf(m1, t.x, a0); a1 = fmaf(m1, t.y, a1);
        t = __half22float2(h1[1]); a2 = fmaf(m1, t.x, a2); a3 = fmaf(m1, t.y, a3);
        t = __half22float2(h1[2]); a4 = fmaf(m1, t.x, a4); a5 = fmaf(m1, t.y, a5);
        t = __half22float2(h1[3]); a6 = fmaf(m1, t.x, a6); a7 = fmaf(m1, t.y, a7);
    }
    // reduce across the 8 edge-slots (lane bits 3..5)
#pragma unroll
    for (int ofs = 8; ofs <= 32; ofs <<= 1) {
        a0 += __shfl_xor(a0, ofs);
        a1 += __shfl_xor(a1, ofs);
        a2 += __shfl_xor(a2, ofs);
        a3 += __shfl_xor(a3, ofs);
        a4 += __shfl_xor(a4, ofs);
        a5 += __shfl_xor(a5, ofs);
        a6 += __shfl_xor(a6, ofs);
        a7 += __shfl_xor(a7, ofs);
    }
    if (g == 0) {
        float dc = dinv[wave];
        if (!LAST) {
            float s = dc * dc;          // y_out = dinv * (dinv * sum)
            float4 pack;
            __half2* ph = (__half2*)&pack;
            ph[0] = __floats2half2_rn(s * a0, s * a1);
            ph[1] = __floats2half2_rn(s * a2, s * a3);
            ph[2] = __floats2half2_rn(s * a4, s * a5);
            ph[3] = __floats2half2_rn(s * a6, s * a7);
            ((float4*)y_out)[(size_t)wave * 8 + q] = pack;
        } else {
            // out = 0.25*(emb + rdinv*(y1+y2) + dinv*sum)
            float rd = rdinv[wave];
            float4 y1r = ((const float4*)y_prev)[(size_t)wave * 8 + q];
            float4 y2r = ((const float4*)y_in)[(size_t)wave * 8 + q];
            const __half2* p1 = (const __half2*)&y1r;
            const __half2* p2 = (const __half2*)&y2r;
            float w[8];
#pragma unroll
            for (int j = 0; j < 4; ++j) {
                float2 u1 = __half22float2(p1[j]);
                float2 u2 = __half22float2(p2[j]);
                w[2 * j]     = u1.x + u2.x;
                w[2 * j + 1] = u1.y + u2.y;
            }
            const float* src = (wave < nU) ? user + (size_t)wave * DIM
                                           : item + (size_t)(wave - nU) * DIM;
            float4 e0 = ((const float4*)src)[q * 2];
            float4 e1 = ((const float4*)src)[q * 2 + 1];
            float4 o0, o1;
            o0.x = 0.25f * (e0.x + rd * w[0] + dc * a0);
            o0.y = 0.25f * (e0.y + rd * w[1] + dc * a1);
            o0.z = 0.25f * (e0.z + rd * w[2] + dc * a2);
            o0.w = 0.25f * (e0.w + rd * w[3] + dc * a3);
            o1.x = 0.25f * (e1.x + rd * w[4] + dc * a4);
            o1.y = 0.25f * (e1.y + rd * w[5] + dc * a5);
            o1.z = 0.25f * (e1.z + rd * w[6] + dc * a6);
            o1.w = 0.25f * (e1.w + rd * w[7] + dc * a7);
            float4* o4 = (float4*)(out + (size_t)wave * DIM + q * 8);
            o4[0] = o0;
            o4[1] = o1;
        }
    }
}

// ---------------- host launcher ----------------

extern "C" void kernel_launch(void* const* d_in, const int* in_sizes, int n_in,
                              void* d_out, int out_size, void* d_ws, size_t ws_size,
                              hipStream_t stream) {
    const float* user = (const float*)d_in[0];
    const float* item = (const float*)d_in[1];
    const int*   edge = (const int*)d_in[2];

    const int nU = in_sizes[0] / DIM;
    const int nI = in_sizes[1] / DIM;
    const int nN = nU + nI;
    const int E  = in_sizes[2] / 2;
    const int NB = (nN + 255) / 256;     // 256-node coarse buckets

    float* out = (float*)d_out;

    // workspace carve-up (256B aligned)
    char* ws = (char*)d_ws;
    size_t off = 0;
    auto take = [&](size_t bytes) -> char* {
        char* p = ws + off;
        off = (off + bytes + 255) & ~(size_t)255;
        return p;
    };
    const size_t ytab = (size_t)nN * DIM * 2;            // fp16 table
    const size_t arena = (size_t)NB * BSTRIDE * 4;       // fixed-stride arena
    int*      bcur       = (int*)  take((size_t)NB * 4);
    int2*     pdesc      = (int2*) take((size_t)nN * 8);
    float*    dinv       = (float*)take((size_t)nN * 4);
    float*    rdinv      = (float*)take((size_t)nN * 4);
    int*      row_sorted = (int*)  take(arena);
    char*     R1 = take(arena > ytab ? arena : ytab);    // bin, then y1
    char*     R2 = take(ytab);                           // y0
    char*     R3 = take(ytab);                           // y2
    unsigned* bin = (unsigned*)R1;
    __half*   y1  = (__half*)R1;
    __half*   y0  = (__half*)R2;
    __half*   y2  = (__half*)R3;
    (void)ws_size; (void)n_in; (void)out_size;

    const int B = 256;
    dim3 blk(B);

    // 1. zero bucket cursors
    zero_ints<<<dim3((NB + B - 1) / B), blk, 0, stream>>>(bcur, NB);
    // 2. LDS-staged scatter into fixed-stride bucket arenas
    bin_kernel<<<dim3((E + BINC - 1) / BINC), dim3(1024), 0, stream>>>(edge, E, bcur, bin, NB);
    // 3. per-bucket counting sort -> CSR + dinv/rdinv + fused y0 init
    csr_kernel<<<dim3(NB), blk, 0, stream>>>(bin, bcur, user, item, nU,
                                             pdesc, dinv, rdinv, row_sorted, y0, nN);

    // 4. three propagation layers; layer 3 fuses the final combine
    dim3 lgrid((nN + 3) / 4);   // 4 waves (nodes) per 256-thread block
    layer_kernel<false><<<lgrid, blk, 0, stream>>>(pdesc, dinv, row_sorted, y0, y1,
                                                   nullptr, nullptr, nullptr, nullptr, nullptr,
                                                   nU, nN);
    layer_kernel<false><<<lgrid, blk, 0, stream>>>(pdesc, dinv, row_sorted, y1, y2,
                                                   nullptr, nullptr, nullptr, nullptr, nullptr,
                                                   nU, nN);
    layer_kernel<true ><<<lgrid, blk, 0, stream>>>(pdesc, dinv, row_sorted, y2, nullptr,
                                                   user, item, rdinv, y1, out,
                                                   nU, nN);
}

// Round 11
// 281.646 us; speedup vs baseline: 1.6983x; 1.0658x over previous
//
#include <hip/hip_runtime.h>
#include <hip/hip_fp16.h>

#define DIM 64
#define BSH 8                 // log2(nodes per bucket) = 256 nodes/bucket
#define BMASK 255u
#define NBMAX 1024            // max coarse buckets supported
#define BINC 16384            // edges staged per bin block
#define BSTRIDE 8192          // fixed arena per bucket (avg 6826, >10 sigma margin)

// ---------------- prep kernels ----------------

__global__ void zero_ints(int* __restrict__ p, int n) {
    int i = blockIdx.x * blockDim.x + threadIdx.x;
    if (i < n) p[i] = 0;
}

// LDS-staged scatter into fixed-stride bucket arenas; entry = (row<<8)|(col&255).
// Reserves one contiguous range per (block,bucket) with a single global atomic.
__global__ __launch_bounds__(1024) void bin_kernel(const int* __restrict__ edge, int E,
                                                   int* __restrict__ bcur,
                                                   unsigned* __restrict__ bin, int NB) {
    __shared__ unsigned stage[BINC];
    __shared__ int lcnt[NBMAX];
    __shared__ int lsc[NBMAX];
    __shared__ int lcur[NBMAX];
    __shared__ int gb[NBMAX];
    const int tid = (int)threadIdx.x;
    const int beg = (int)blockIdx.x * BINC;
    const int n = min(BINC, E - beg);

    lcnt[tid] = 0;
    __syncthreads();
    // phase 1: count per bucket
    for (int i = tid; i < n; i += 1024)
        atomicAdd(&lcnt[edge[E + beg + i] >> BSH], 1);
    __syncthreads();
    // inclusive scan over 1024 slots
    lsc[tid] = lcnt[tid];
    __syncthreads();
    for (int off = 1; off < 1024; off <<= 1) {
        int t = (tid >= off) ? lsc[tid - off] : 0;
        __syncthreads();
        lsc[tid] += t;
        __syncthreads();
    }
    // reserve per-bucket global ranges (fixed-stride arenas)
    {
        int cb = lcnt[tid];
        lcur[tid] = lsc[tid] - cb;
        if (tid < NB) gb[tid] = cb ? atomicAdd(&bcur[tid], cb) : 0;
    }
    __syncthreads();
    // phase 2: rank into LDS stage (sorted by bucket)
    for (int i = tid; i < n; i += 1024) {
        int r = edge[beg + i];
        int c = edge[E + beg + i];
        int b = c >> BSH;
        int slot = atomicAdd(&lcur[b], 1);
        stage[slot] = ((unsigned)r << BSH) | ((unsigned)c & BMASK);
    }
    __syncthreads();
    // phase 3: per-bucket coalesced copy out into the bucket arena
    const int wid = tid >> 6, lane = tid & 63;
    for (int b = wid; b < NB; b += 16) {
        int cb = lcnt[b];
        if (!cb) continue;
        int lb = lsc[b] - cb;
        int g = b * BSTRIDE + gb[b];
        for (int l = lane; l < cb; l += 64)
            bin[g + l] = stage[lb + l];
    }
}

// per-bucket counting sort (bin staged in LDS once) -> CSR + pdesc + dinv/rdinv,
// fused y0 init (y0 = fp16(dinv * emb))
__global__ __launch_bounds__(256) void csr_kernel(const unsigned* __restrict__ bin,
                                                  const int* __restrict__ bcnt,
                                                  const float* __restrict__ user,
                                                  const float* __restrict__ item,
                                                  int nU,
                                                  int2* __restrict__ pdesc,
                                                  float* __restrict__ dinv,
                                                  float* __restrict__ rdinv,
                                                  int* __restrict__ row_sorted,
                                                  __half* __restrict__ y0,
                                                  int nN) {
    __shared__ unsigned sbin[BSTRIDE];
    __shared__ int lcnt[256];
    __shared__ int lsc[256];
    __shared__ int lcur[256];
    __shared__ float sdinv[256];
    const int tid = (int)threadIdx.x;
    const int b = (int)blockIdx.x;
    const int abase = b * BSTRIDE;
    const int cnt = bcnt[b];
    lcnt[tid] = 0;
    // stage this bucket's entries in LDS (single global read)
    for (int i = tid; i < cnt; i += 256)
        sbin[i] = bin[abase + i];
    __syncthreads();
    for (int i = tid; i < cnt; i += 256)
        atomicAdd(&lcnt[sbin[i] & BMASK], 1);
    __syncthreads();
    lsc[tid] = lcnt[tid];
    __syncthreads();
    for (int off = 1; off < 256; off <<= 1) {
        int t = (tid >= off) ? lsc[tid - off] : 0;
        __syncthreads();
        lsc[tid] += t;
        __syncthreads();
    }
    const int cb = lcnt[tid];
    const int lb = lsc[tid] - cb;
    lcur[tid] = abase + lb;
    float dv = cb ? rsqrtf((float)cb) : 0.0f;
    sdinv[tid] = dv;
    int node = (b << BSH) + tid;
    if (node < nN) {
        pdesc[node] = make_int2(abase + lb, cb);
        dinv[node] = dv;
        rdinv[node] = cb ? sqrtf((float)cb) : 0.0f;
    }
    __syncthreads();
    for (int i = tid; i < cnt; i += 256) {
        unsigned e = sbin[i];
        int c = (int)(e & BMASK);
        int p = atomicAdd(&lcur[c], 1);
        row_sorted[p] = (int)(e >> BSH);
    }
    // fused y0 init: 256 nodes x 8 chunks; chunk qc covers dims 8qc..8qc+7
    const int baseNode = b << BSH;
#pragma unroll
    for (int it = 0; it < 8; ++it) {
        int idx = it * 256 + tid;
        int ln = idx >> 3;
        int node2 = baseNode + ln;
        if (node2 < nN) {
            int qc = idx & 7;
            const float* src = (node2 < nU) ? user + (size_t)node2 * DIM
                                            : item + (size_t)(node2 - nU) * DIM;
            float4 e0 = ((const float4*)src)[qc * 2];
            float4 e1 = ((const float4*)src)[qc * 2 + 1];
            float dvn = sdinv[ln];
            float4 pack;
            __half2* p = (__half2*)&pack;
            p[0] = __floats2half2_rn(dvn * e0.x, dvn * e0.y);
            p[1] = __floats2half2_rn(dvn * e0.z, dvn * e0.w);
            p[2] = __floats2half2_rn(dvn * e1.x, dvn * e1.y);
            p[3] = __floats2half2_rn(dvn * e1.z, dvn * e1.w);
            ((float4*)y0)[(size_t)baseNode * 8 + idx] = pack;
        }
    }
}

// zero the shared pad row (row nN) of the three y tables
__global__ void zero_row_kernel(__half* __restrict__ r1, __half* __restrict__ r2,
                                __half* __restrict__ r3, int nN) {
    int t = threadIdx.x;       // 64 threads
    size_t o = (size_t)nN * DIM + t;
    r1[o] = __float2half(0.0f);
    r2[o] = __float2half(0.0f);
    r3[o] = __float2half(0.0f);
}

// one wave per node; 8 edge-slots x 8 lanes; lane loads float4 (8 halves);
// 32 edges (4KB) in flight; tail slots gather the shared zero row (index nN)
// -> maskless packed-fp16 accumulate (v_pk_add_f16, 4 VALU per 16B vs 16).
// LAST fuses the final combine: out = 0.25*(emb + rdinv*(y1+y2) + dinv*sum).
template<bool LAST>
__global__ __launch_bounds__(256) void layer_kernel(const int2* __restrict__ pdesc,
                                                    const float* __restrict__ dinv,
                                                    const int* __restrict__ row_sorted,
                                                    const __half* __restrict__ y_in,
                                                    __half* __restrict__ y_out,
                                                    const float* __restrict__ user,
                                                    const float* __restrict__ item,
                                                    const float* __restrict__ rdinv,
                                                    const __half* __restrict__ y_prev,
                                                    float* __restrict__ out,
                                                    int nU, int nN) {
    int wave = (int)((blockIdx.x * blockDim.x + threadIdx.x) >> 6);
    int lane = (int)(threadIdx.x & 63);
    if (wave >= nN) return;
    const int2 pd = pdesc[wave];
    const int beg = pd.x;
    const int n = pd.y;
    const int zrow = nN;
    const int g = lane >> 3;   // edge slot 0..7
    const int q = lane & 7;    // 16B chunk of the row, 0..7
    const float4* yv = (const float4*)y_in;
    __half2 acc0 = __float2half2_rn(0.0f);
    __half2 acc1 = acc0, acc2 = acc0, acc3 = acc0;
    for (int base = 0; base < n; base += 32) {
        int s = base + g;
        int e = beg + s;
        int i0 = (s      < n) ? row_sorted[e]      : zrow;
        int i1 = (s + 8  < n) ? row_sorted[e + 8]  : zrow;
        int i2 = (s + 16 < n) ? row_sorted[e + 16] : zrow;
        int i3 = (s + 24 < n) ? row_sorted[e + 24] : zrow;
        float4 v0 = yv[(size_t)i0 * 8 + q];
        float4 v1 = yv[(size_t)i1 * 8 + q];
        float4 v2 = yv[(size_t)i2 * 8 + q];
        float4 v3 = yv[(size_t)i3 * 8 + q];
        const __half2* h0 = (const __half2*)&v0;
        const __half2* h1 = (const __half2*)&v1;
        const __half2* h2 = (const __half2*)&v2;
        const __half2* h3 = (const __half2*)&v3;
        acc0 = __hadd2(acc0, h0[0]); acc1 = __hadd2(acc1, h0[1]);
        acc2 = __hadd2(acc2, h0[2]); acc3 = __hadd2(acc3, h0[3]);
        acc0 = __hadd2(acc0, h1[0]); acc1 = __hadd2(acc1, h1[1]);
        acc2 = __hadd2(acc2, h1[2]); acc3 = __hadd2(acc3, h1[3]);
        acc0 = __hadd2(acc0, h2[0]); acc1 = __hadd2(acc1, h2[1]);
        acc2 = __hadd2(acc2, h2[2]); acc3 = __hadd2(acc3, h2[3]);
        acc0 = __hadd2(acc0, h3[0]); acc1 = __hadd2(acc1, h3[1]);
        acc2 = __hadd2(acc2, h3[2]); acc3 = __hadd2(acc3, h3[3]);
    }
    // reduce across the 8 edge-slots (lane bits 3..5), packed fp16
#pragma unroll
    for (int ofs = 8; ofs <= 32; ofs <<= 1) {
        int t0 = __shfl_xor(*reinterpret_cast<int*>(&acc0), ofs);
        int t1 = __shfl_xor(*reinterpret_cast<int*>(&acc1), ofs);
        int t2 = __shfl_xor(*reinterpret_cast<int*>(&acc2), ofs);
        int t3 = __shfl_xor(*reinterpret_cast<int*>(&acc3), ofs);
        acc0 = __hadd2(acc0, *reinterpret_cast<__half2*>(&t0));
        acc1 = __hadd2(acc1, *reinterpret_cast<__half2*>(&t1));
        acc2 = __hadd2(acc2, *reinterpret_cast<__half2*>(&t2));
        acc3 = __hadd2(acc3, *reinterpret_cast<__half2*>(&t3));
    }
    if (g == 0) {
        float dc = dinv[wave];
        float2 s0 = __half22float2(acc0);
        float2 s1 = __half22float2(acc1);
        float2 s2 = __half22float2(acc2);
        float2 s3 = __half22float2(acc3);
        if (!LAST) {
            float s = dc * dc;          // y_out = dinv * (dinv * sum)
            float4 pack;
            __half2* ph = (__half2*)&pack;
            ph[0] = __floats2half2_rn(s * s0.x, s * s0.y);
            ph[1] = __floats2half2_rn(s * s1.x, s * s1.y);
            ph[2] = __floats2half2_rn(s * s2.x, s * s2.y);
            ph[3] = __floats2half2_rn(s * s3.x, s * s3.y);
            ((float4*)y_out)[(size_t)wave * 8 + q] = pack;
        } else {
            // out = 0.25*(emb + rdinv*(y1+y2) + dinv*sum)
            float rd = rdinv[wave];
            float4 y1r = ((const float4*)y_prev)[(size_t)wave * 8 + q];
            float4 y2r = ((const float4*)y_in)[(size_t)wave * 8 + q];
            const __half2* p1 = (const __half2*)&y1r;
            const __half2* p2 = (const __half2*)&y2r;
            float w[8];
#pragma unroll
            for (int j = 0; j < 4; ++j) {
                float2 u1 = __half22float2(p1[j]);
                float2 u2 = __half22float2(p2[j]);
                w[2 * j]     = u1.x + u2.x;
                w[2 * j + 1] = u1.y + u2.y;
            }
            const float* src = (wave < nU) ? user + (size_t)wave * DIM
                                           : item + (size_t)(wave - nU) * DIM;
            float4 e0 = ((const float4*)src)[q * 2];
            float4 e1 = ((const float4*)src)[q * 2 + 1];
            float4 o0, o1;
            o0.x = 0.25f * (e0.x + rd * w[0] + dc * s0.x);
            o0.y = 0.25f * (e0.y + rd * w[1] + dc * s0.y);
            o0.z = 0.25f * (e0.z + rd * w[2] + dc * s1.x);
            o0.w = 0.25f * (e0.w + rd * w[3] + dc * s1.y);
            o1.x = 0.25f * (e1.x + rd * w[4] + dc * s2.x);
            o1.y = 0.25f * (e1.y + rd * w[5] + dc * s2.y);
            o1.z = 0.25f * (e1.z + rd * w[6] + dc * s3.x);
            o1.w = 0.25f * (e1.w + rd * w[7] + dc * s3.y);
            float4* o4 = (float4*)(out + (size_t)wave * DIM + q * 8);
            o4[0] = o0;
            o4[1] = o1;
        }
    }
}

// ---------------- host launcher ----------------

extern "C" void kernel_launch(void* const* d_in, const int* in_sizes, int n_in,
                              void* d_out, int out_size, void* d_ws, size_t ws_size,
                              hipStream_t stream) {
    const float* user = (const float*)d_in[0];
    const float* item = (const float*)d_in[1];
    const int*   edge = (const int*)d_in[2];

    const int nU = in_sizes[0] / DIM;
    const int nI = in_sizes[1] / DIM;
    const int nN = nU + nI;
    const int E  = in_sizes[2] / 2;
    const int NB = (nN + 255) / 256;     // 256-node coarse buckets

    float* out = (float*)d_out;

    // workspace carve-up (256B aligned)
    char* ws = (char*)d_ws;
    size_t off = 0;
    auto take = [&](size_t bytes) -> char* {
        char* p = ws + off;
        off = (off + bytes + 255) & ~(size_t)255;
        return p;
    };
    const size_t ytab = (size_t)(nN + 1) * DIM * 2;      // fp16 table + zero row
    const size_t arena = (size_t)NB * BSTRIDE * 4;       // fixed-stride arena
    int*      bcur       = (int*)  take((size_t)NB * 4);
    int2*     pdesc      = (int2*) take((size_t)nN * 8);
    float*    dinv       = (float*)take((size_t)nN * 4);
    float*    rdinv      = (float*)take((size_t)nN * 4);
    int*      row_sorted = (int*)  take(arena);
    char*     R1 = take(arena > ytab ? arena : ytab);    // bin, then y1
    char*     R2 = take(ytab);                           // y0
    char*     R3 = take(ytab);                           // y2
    unsigned* bin = (unsigned*)R1;
    __half*   y1  = (__half*)R1;
    __half*   y0  = (__half*)R2;
    __half*   y2  = (__half*)R3;
    (void)ws_size; (void)n_in; (void)out_size;

    const int B = 256;
    dim3 blk(B);

    // 1. zero bucket cursors
    zero_ints<<<dim3((NB + B - 1) / B), blk, 0, stream>>>(bcur, NB);
    // 2. LDS-staged scatter into fixed-stride bucket arenas
    bin_kernel<<<dim3((E + BINC - 1) / BINC), dim3(1024), 0, stream>>>(edge, E, bcur, bin, NB);
    // 3. per-bucket counting sort -> CSR + dinv/rdinv + fused y0 init
    csr_kernel<<<dim3(NB), blk, 0, stream>>>(bin, bcur, user, item, nU,
                                             pdesc, dinv, rdinv, row_sorted, y0, nN);
    // 3b. zero the shared pad row (after bin is consumed; y1 aliases bin)
    zero_row_kernel<<<dim3(1), dim3(64), 0, stream>>>(y0, y1, y2, nN);

    // 4. three propagation layers; layer 3 fuses the final combine
    dim3 lgrid((nN + 3) / 4);   // 4 waves (nodes) per 256-thread block
    layer_kernel<false><<<lgrid, blk, 0, stream>>>(pdesc, dinv, row_sorted, y0, y1,
                                                   nullptr, nullptr, nullptr, nullptr, nullptr,
                                                   nU, nN);
    layer_kernel<false><<<lgrid, blk, 0, stream>>>(pdesc, dinv, row_sorted, y1, y2,
                                                   nullptr, nullptr, nullptr, nullptr, nullptr,
                                                   nU, nN);
    layer_kernel<true ><<<lgrid, blk, 0, stream>>>(pdesc, dinv, row_sorted, y2, nullptr,
                                                   user, item, rdinv, y1, out,
                                                   nU, nN);
}